// Round 13
// baseline (224.303 us; speedup 1.0000x reference)
//
#include <hip/hip_runtime.h>
#include <hip/hip_bf16.h>
#include <math.h>

#define NB  1024
#define NN  1000
#define NE  128
#define NH  8
#define NDK 16
#define NSC 256

typedef __attribute__((ext_vector_type(4))) float f32x4;

__device__ __forceinline__ f32x4 ld4(const float* p) {
    return *reinterpret_cast<const f32x4*>(p);
}

// ---------------- kernel 0: query[b][e] = ctx + stepc @ Wstep^T ----------------
__global__ __launch_bounds__(128)
void query_kernel(const float* __restrict__ ctx, const float* __restrict__ stepc,
                  const float* __restrict__ Wstep, float* __restrict__ q_ws)
{
    const int b = blockIdx.x, t = threadIdx.x;
    __shared__ float sc[NSC];
    sc[t] = stepc[b * NSC + t];
    sc[t + 128] = stepc[b * NSC + t + 128];
    __syncthreads();
    float acc = ctx[b * NE + t];
    const float4* w4 = reinterpret_cast<const float4*>(Wstep + (size_t)t * NSC);
    #pragma unroll 8
    for (int c4 = 0; c4 < NSC / 4; ++c4) {
        float4 w = w4[c4];
        acc += sc[4*c4] * w.x + sc[4*c4+1] * w.y + sc[4*c4+2] * w.z + sc[4*c4+3] * w.w;
    }
    q_ws[b * NE + t] = acc;
}

// ---------------- fused kernel: one block per b; BARRIER-FREE head loop ----------------
// Wave w processes rows {w*16 + i*128 + rsl} of every head with per-lane online softmax;
// per-(head,wave) partials {m, ls, acc} land in disjoint LDS; ONE barrier; rescale-merge.
// K/V: mask-skip dummy-row-0 loads (proven regime), 2 half-bursts of 4 K + 4 V
// to keep peak live registers < 64 (R11's spill lesson).
__global__ __launch_bounds__(512, 4)
void fused_kernel(const float* __restrict__ q_ws,
                  const float* __restrict__ gK, const float* __restrict__ gV,
                  const float* __restrict__ lK, const float* __restrict__ Wout,
                  const unsigned char* __restrict__ mask,
                  __hip_bfloat16* __restrict__ out)
{
    const int b = blockIdx.x;
    const int t = threadIdx.x;
    const int w = t >> 6, lane = t & 63;
    const int qq  = lane & 3;             // dk-quarter 0..3
    const int rsl = lane >> 2;            // row slot 0..15

    __shared__ float m_l[NH][8], ls_l[NH][8];
    __shared__ __align__(16) float acc_l[NH][8][16];
    __shared__ __align__(16) float g[NE];       // concat heads
    __shared__ __align__(16) float gout[NE];
    __shared__ float red[8];
    __shared__ float Mv, LSv;

    // mask dtype detect (wave-uniform): first 64 words all <=1 -> int32 mask
    const unsigned int* mw = reinterpret_cast<const unsigned int*>(mask);
    const bool m_i32 = (__ballot(mw[lane] <= 1u) == ~0ull);
    const int* mask_i = reinterpret_cast<const int*>(mask);

    // ---- row-mask bits: loaded ONCE, reused by all 8 heads ----
    unsigned mbits = 0;
    #pragma unroll
    for (int i = 0; i < 8; ++i) {
        const int n = w * 16 + i * 128 + rsl;
        const bool dead = (n >= NN);
        const int nn = dead ? 0 : n;
        int mk = m_i32 ? (mask_i[(size_t)b * NN + nn] != 0)
                       : (mask[(size_t)b * NN + nn] != 0);
        mbits |= (unsigned)(mk | (dead ? 1 : 0)) << i;
    }

    // ---- attention: 8 heads, ZERO barriers ----
    #pragma unroll 1
    for (int h = 0; h < NH; ++h) {
        const f32x4 qv = ld4(q_ws + (size_t)b * NE + h * NDK + qq * 4);
        const float* Kb = gK + (size_t)(h * NB + b) * NN * NDK;
        const float* Vb = gV + (size_t)(h * NB + b) * NN * NDK;

        float m = -3.0e38f, ls = 0.f;      // finite init: exp(m-mn) never NaN
        f32x4 acc = {0.f, 0.f, 0.f, 0.f};

        #pragma unroll
        for (int half = 0; half < 2; ++half) {
            f32x4 kv[4], vv[4];
            #pragma unroll
            for (int j = 0; j < 4; ++j) {
                const int i = half * 4 + j;
                const int n = w * 16 + i * 128 + rsl;
                const int nn = ((mbits >> i) & 1u) ? 0 : n;   // masked -> hot dummy row 0
                const size_t off = (size_t)nn * NDK + qq * 4;
                kv[j] = ld4(Kb + off);
                vv[j] = ld4(Vb + off);
            }
            float s[4];
            #pragma unroll
            for (int j = 0; j < 4; ++j) {
                const int i = half * 4 + j;
                float p = kv[j].x*qv.x + kv[j].y*qv.y + kv[j].z*qv.z + kv[j].w*qv.w;
                p += __shfl_xor(p, 1);
                p += __shfl_xor(p, 2);          // quad lanes hold full dot
                s[j] = ((mbits >> i) & 1u) ? -INFINITY : p * 0.25f;  // 1/sqrt(16)
            }
            // per-lane online merge of this half-burst
            const float bm = fmaxf(fmaxf(s[0], s[1]), fmaxf(s[2], s[3]));  // may be -inf
            const float mn = fmaxf(m, bm);                                 // >= -3e38, finite
            const float corr = __expf(m - mn);     // 1 if unchanged; 0 wipes empty acc
            ls *= corr;
            acc.x *= corr; acc.y *= corr; acc.z *= corr; acc.w *= corr;
            #pragma unroll
            for (int j = 0; j < 4; ++j) {
                const float e = __expf(s[j] - mn);   // exp(-inf)=0 for masked
                ls += e;
                acc.x += e * vv[j].x; acc.y += e * vv[j].y;
                acc.z += e * vv[j].z; acc.w += e * vv[j].w;
            }
            m = mn;
        }

        // ---- wave-local reduce over the 16 row-slot groups (quad lanes duplicate) ----
        float mw_ = m;
        #pragma unroll
        for (int off = 4; off < 64; off <<= 1) mw_ = fmaxf(mw_, __shfl_xor(mw_, off));
        const float f = __expf(m - mw_);     // m==mw_==-3e38 -> exp(0)=1, ls=0: harmless
        ls *= f;
        acc.x *= f; acc.y *= f; acc.z *= f; acc.w *= f;
        #pragma unroll
        for (int off = 4; off < 64; off <<= 1) {
            ls    += __shfl_xor(ls, off);    // exact sum: quad copies counted once each
            acc.x += __shfl_xor(acc.x, off);
            acc.y += __shfl_xor(acc.y, off);
            acc.z += __shfl_xor(acc.z, off);
            acc.w += __shfl_xor(acc.w, off);
        }
        if (rsl == 0) {                      // lanes 0..3 (qq = 0..3), disjoint LDS
            *reinterpret_cast<f32x4*>(&acc_l[h][w][qq * 4]) = acc;
            if (qq == 0) { m_l[h][w] = mw_; ls_l[h][w] = ls; }
        }
    }
    __syncthreads();                         // the ONLY barrier before the tail

    // ---- rescale-merge 8 waves' partials per head (t < 128: one (h,k) each) ----
    if (t < NE) {
        const int h = t >> 4, k = t & 15;
        float M = m_l[h][0];
        #pragma unroll
        for (int i = 1; i < 8; ++i) M = fmaxf(M, m_l[h][i]);
        float num = 0.f, den = 0.f;
        #pragma unroll
        for (int i = 0; i < 8; ++i) {
            const float fw = __expf(m_l[h][i] - M);   // 0 for empty waves (m=-3e38)
            num += acc_l[h][i][k] * fw;
            den += ls_l[h][i] * fw;
        }
        g[t] = num / den;                    // den > 0: node 0 always unmasked
    }
    __syncthreads();

    // ---------------- logits tail (proven R9 structure) ----------------
    if (t < NE) {
        float a2 = 0.f;
        const float4* w4 = reinterpret_cast<const float4*>(Wout + (size_t)t * NE);
        const float4* g4 = reinterpret_cast<const float4*>(g);
        #pragma unroll 8
        for (int e4 = 0; e4 < NE / 4; ++e4) {
            float4 wv = w4[e4]; float4 gg = g4[e4];
            a2 += wv.x*gg.x + wv.y*gg.y + wv.z*gg.z + wv.w*gg.w;
        }
        gout[t] = a2;
    }
    __syncthreads();

    const f32x4* go4 = reinterpret_cast<const f32x4*>(gout);
    float lv[2];
    #pragma unroll
    for (int i = 0; i < 2; ++i) {
        const int n = t + 512 * i;
        const bool live = (n < NN);
        const int nidx = live ? n : 0;
        int mkd = m_i32 ? (mask_i[(size_t)b * NN + nidx] != 0)
                        : (mask[(size_t)b * NN + nidx] != 0);
        mkd |= (live ? 0 : 1);
        const int nn = mkd ? 0 : n;
        const float* lp = lK + ((size_t)b * NN + nn) * NE;
        float a3 = 0.f;
        #pragma unroll
        for (int c4 = 0; c4 < NE / 4; ++c4) {
            f32x4 x = ld4(lp + 4 * c4);
            f32x4 gv = go4[c4];                 // broadcast LDS read
            a3 += x.x*gv.x + x.y*gv.y + x.z*gv.z + x.w*gv.w;
        }
        float val = tanhf(a3 * 0.08838834764831845f) * 10.0f;  // 1/sqrt(128), clip 10
        lv[i] = mkd ? -3.0e38f : val;   // finite sentinel (NaN-free compare vs ref -inf)
    }

    float mm = fmaxf(lv[0], lv[1]);
    #pragma unroll
    for (int off = 32; off > 0; off >>= 1) mm = fmaxf(mm, __shfl_xor(mm, off));
    if (lane == 0) red[w] = mm;
    __syncthreads();
    if (t == 0) {
        float m2 = red[0];
        #pragma unroll
        for (int i = 1; i < 8; ++i) m2 = fmaxf(m2, red[i]);
        Mv = m2;
    }
    __syncthreads();
    const float M2 = Mv;
    float s2 = expf(lv[0] - M2) + expf(lv[1] - M2);   // exp(-3e38 - M) == 0
    #pragma unroll
    for (int off = 32; off > 0; off >>= 1) s2 += __shfl_xor(s2, off);
    if (lane == 0) red[w] = s2;
    __syncthreads();
    if (t == 0) {
        float ss = 0.f;
        #pragma unroll
        for (int i = 0; i < 8; ++i) ss += red[i];
        LSv = M2 + logf(ss);
    }
    __syncthreads();
    const float LS = LSv;
    #pragma unroll
    for (int i = 0; i < 2; ++i) {
        const int n = t + 512 * i;
        if (n < NN)
            out[(size_t)b * NN + n] = __float2bfloat16(lv[i] - LS);  // -3e38-LS stays -3e38
    }
}

extern "C" void kernel_launch(void* const* d_in, const int* in_sizes, int n_in,
                              void* d_out, int out_size, void* d_ws, size_t ws_size,
                              hipStream_t stream) {
    const float* ctx   = (const float*)d_in[0];
    const float* stepc = (const float*)d_in[1];
    const float* Wstep = (const float*)d_in[2];
    const float* gK    = (const float*)d_in[3];
    const float* gV    = (const float*)d_in[4];
    const float* lK    = (const float*)d_in[5];
    const float* Wout  = (const float*)d_in[6];
    const unsigned char* mask = (const unsigned char*)d_in[7];
    __hip_bfloat16* out = (__hip_bfloat16*)d_out;

    float* q_ws = (float*)d_ws;   // 512 KB
    query_kernel<<<dim3(NB), dim3(128), 0, stream>>>(ctx, stepc, Wstep, q_ws);
    fused_kernel<<<dim3(NB), dim3(512), 0, stream>>>(q_ws, gK, gV, lK, Wout, mask, out);
}

// Round 14
// 220.233 us; speedup vs baseline: 1.0185x; 1.0185x over previous
//
#include <hip/hip_runtime.h>
#include <hip/hip_bf16.h>
#include <math.h>

#define NB  1024
#define NN  1000
#define NE  128
#define NH  8
#define NDK 16
#define NSC 256

typedef __attribute__((ext_vector_type(4))) float f32x4;

__device__ __forceinline__ f32x4 ld4(const float* p) {
    return *reinterpret_cast<const f32x4*>(p);
}

// ---------------- kernel 0: query[b][e] = ctx + stepc @ Wstep^T ----------------
__global__ __launch_bounds__(128)
void query_kernel(const float* __restrict__ ctx, const float* __restrict__ stepc,
                  const float* __restrict__ Wstep, float* __restrict__ q_ws)
{
    const int b = blockIdx.x, t = threadIdx.x;
    __shared__ float sc[NSC];
    sc[t] = stepc[b * NSC + t];
    sc[t + 128] = stepc[b * NSC + t + 128];
    __syncthreads();
    float acc = ctx[b * NE + t];
    const float4* w4 = reinterpret_cast<const float4*>(Wstep + (size_t)t * NSC);
    #pragma unroll 8
    for (int c4 = 0; c4 < NSC / 4; ++c4) {
        float4 w = w4[c4];
        acc += sc[4*c4] * w.x + sc[4*c4+1] * w.y + sc[4*c4+2] * w.z + sc[4*c4+3] * w.w;
    }
    q_ws[b * NE + t] = acc;
}

// ---------------- fused kernel: one block per b; attn (8 heads) + logits, all block-local ----------------
// Proven best (R9/R12: 219.9 us). 512 thr = 8 waves; grid 1024 = 4 blocks/CU.
// 4 lanes/row, fused mask-predicated K+V burst (skip -> dummy row 0), shfl reductions,
// parity LDS double-buffer (2 barriers/head), then logits tail.
__global__ __launch_bounds__(512, 4)
void fused_kernel(const float* __restrict__ q_ws,
                  const float* __restrict__ gK, const float* __restrict__ gV,
                  const float* __restrict__ lK, const float* __restrict__ Wout,
                  const unsigned char* __restrict__ mask,
                  __hip_bfloat16* __restrict__ out)
{
    const int b = blockIdx.x;
    const int t = threadIdx.x;
    const int w = t >> 6, lane = t & 63;
    const int qq  = lane & 3;             // dk-quarter 0..3
    const int rsl = lane >> 2;            // row slot 0..15

    __shared__ float wmax[2][8], wsum[2][8];
    __shared__ __align__(16) float wred[2][8][16];
    __shared__ __align__(16) float g[NE];       // concat heads
    __shared__ __align__(16) float gout[NE];
    __shared__ float red[8];
    __shared__ float Mv, LSv;

    // mask dtype detect (wave-uniform): first 64 words all <=1 -> int32 mask
    const unsigned int* mw = reinterpret_cast<const unsigned int*>(mask);
    const bool m_i32 = (__ballot(mw[lane] <= 1u) == ~0ull);
    const int* mask_i = reinterpret_cast<const int*>(mask);

    // ---- row-mask bits: loaded ONCE, reused by all 8 heads ----
    unsigned mbits = 0;
    #pragma unroll
    for (int i = 0; i < 8; ++i) {
        const int n = w * 16 + i * 128 + rsl;
        const bool dead = (n >= NN);
        const int nn = dead ? 0 : n;
        int mk = m_i32 ? (mask_i[(size_t)b * NN + nn] != 0)
                       : (mask[(size_t)b * NN + nn] != 0);
        mbits |= (unsigned)(mk | (dead ? 1 : 0)) << i;
    }

    // ---- attention, head-sequential; parity LDS double-buffer -> 2 barriers/head ----
    #pragma unroll 1
    for (int h = 0; h < NH; ++h) {
        const int pb = h & 1;
        const f32x4 qv = ld4(q_ws + (size_t)b * NE + h * NDK + qq * 4);
        const float* Kb = gK + (size_t)(h * NB + b) * NN * NDK;
        const float* Vb = gV + (size_t)(h * NB + b) * NN * NDK;

        f32x4 vreg[8];
        float sc[8];
        #pragma unroll
        for (int i = 0; i < 8; ++i) {
            const int n = w * 16 + i * 128 + rsl;
            const int nn = ((mbits >> i) & 1u) ? 0 : n;   // masked -> hot dummy row 0
            const size_t off = (size_t)nn * NDK + qq * 4;
            f32x4 kv = ld4(Kb + off);
            vreg[i] = ld4(Vb + off);
            sc[i] = kv.x*qv.x + kv.y*qv.y + kv.z*qv.z + kv.w*qv.w;
        }
        #pragma unroll
        for (int i = 0; i < 8; ++i) {
            float p = sc[i];
            p += __shfl_xor(p, 1);
            p += __shfl_xor(p, 2);          // all 4 quad lanes hold full dot
            sc[i] = ((mbits >> i) & 1u) ? -INFINITY : p * 0.25f;   // 1/sqrt(16)
        }

        float m = sc[0];
        #pragma unroll
        for (int i = 1; i < 8; ++i) m = fmaxf(m, sc[i]);
        #pragma unroll
        for (int off = 32; off > 0; off >>= 1) m = fmaxf(m, __shfl_xor(m, off));
        if (lane == 0) wmax[pb][w] = m;
        __syncthreads();
        float M = wmax[pb][0];
        #pragma unroll
        for (int i = 1; i < 8; ++i) M = fmaxf(M, wmax[pb][i]);

        f32x4 acc = {0.f, 0.f, 0.f, 0.f};
        float ls = 0.f;
        #pragma unroll
        for (int i = 0; i < 8; ++i) {
            const float e = expf(sc[i] - M);   // exp(-inf)=0 for masked
            ls += e;
            acc.x += e * vreg[i].x; acc.y += e * vreg[i].y;
            acc.z += e * vreg[i].z; acc.w += e * vreg[i].w;
        }
        #pragma unroll
        for (int off = 32; off > 0; off >>= 1) ls += __shfl_xor(ls, off);
        if (lane == 0) wsum[pb][w] = ls;       // = 4 * true wave sum (quad duplication)

        #pragma unroll
        for (int off = 4; off < 64; off <<= 1) {
            acc.x += __shfl_xor(acc.x, off);
            acc.y += __shfl_xor(acc.y, off);
            acc.z += __shfl_xor(acc.z, off);
            acc.w += __shfl_xor(acc.w, off);
        }
        if (lane < 4) *reinterpret_cast<f32x4*>(&wred[pb][w][lane * 4]) = acc;
        __syncthreads();

        if (t < NDK) {
            float S = wsum[pb][0];
            #pragma unroll
            for (int i = 1; i < 8; ++i) S += wsum[pb][i];
            S *= 0.25f;
            float r = wred[pb][0][t];
            #pragma unroll
            for (int i = 1; i < 8; ++i) r += wred[pb][i][t];
            g[h * NDK + t] = r / S;
        }
        // safe without extra barrier: next head writes the OTHER parity buffers,
        // and this head's g-write lands before this thread's next barrier.
    }
    __syncthreads();                            // g[128] complete

    // ---------------- logits tail (proven structure) ----------------
    if (t < NE) {
        float a2 = 0.f;
        const float4* w4 = reinterpret_cast<const float4*>(Wout + (size_t)t * NE);
        const float4* g4 = reinterpret_cast<const float4*>(g);
        #pragma unroll 8
        for (int e4 = 0; e4 < NE / 4; ++e4) {
            float4 wv = w4[e4]; float4 gg = g4[e4];
            a2 += wv.x*gg.x + wv.y*gg.y + wv.z*gg.z + wv.w*gg.w;
        }
        gout[t] = a2;
    }
    __syncthreads();

    const f32x4* go4 = reinterpret_cast<const f32x4*>(gout);
    float lv[2];
    #pragma unroll
    for (int i = 0; i < 2; ++i) {
        const int n = t + 512 * i;
        const bool live = (n < NN);
        const int nidx = live ? n : 0;
        int mkd = m_i32 ? (mask_i[(size_t)b * NN + nidx] != 0)
                        : (mask[(size_t)b * NN + nidx] != 0);
        mkd |= (live ? 0 : 1);
        const int nn = mkd ? 0 : n;
        const float* lp = lK + ((size_t)b * NN + nn) * NE;
        float a3 = 0.f;
        #pragma unroll
        for (int c4 = 0; c4 < NE / 4; ++c4) {
            f32x4 x = ld4(lp + 4 * c4);
            f32x4 gv = go4[c4];                 // broadcast LDS read
            a3 += x.x*gv.x + x.y*gv.y + x.z*gv.z + x.w*gv.w;
        }
        float val = tanhf(a3 * 0.08838834764831845f) * 10.0f;  // 1/sqrt(128), clip 10
        lv[i] = mkd ? -3.0e38f : val;   // finite sentinel (NaN-free compare vs ref -inf)
    }

    float mm = fmaxf(lv[0], lv[1]);
    #pragma unroll
    for (int off = 32; off > 0; off >>= 1) mm = fmaxf(mm, __shfl_xor(mm, off));
    if (lane == 0) red[w] = mm;
    __syncthreads();
    if (t == 0) {
        float m2 = red[0];
        #pragma unroll
        for (int i = 1; i < 8; ++i) m2 = fmaxf(m2, red[i]);
        Mv = m2;
    }
    __syncthreads();
    const float M2 = Mv;
    float s2 = expf(lv[0] - M2) + expf(lv[1] - M2);   // exp(-3e38 - M) == 0
    #pragma unroll
    for (int off = 32; off > 0; off >>= 1) s2 += __shfl_xor(s2, off);
    if (lane == 0) red[w] = s2;
    __syncthreads();
    if (t == 0) {
        float ss = 0.f;
        #pragma unroll
        for (int i = 0; i < 8; ++i) ss += red[i];
        LSv = M2 + logf(ss);
    }
    __syncthreads();
    const float LS = LSv;
    #pragma unroll
    for (int i = 0; i < 2; ++i) {
        const int n = t + 512 * i;
        if (n < NN)
            out[(size_t)b * NN + n] = __float2bfloat16(lv[i] - LS);  // -3e38-LS stays -3e38
    }
}

extern "C" void kernel_launch(void* const* d_in, const int* in_sizes, int n_in,
                              void* d_out, int out_size, void* d_ws, size_t ws_size,
                              hipStream_t stream) {
    const float* ctx   = (const float*)d_in[0];
    const float* stepc = (const float*)d_in[1];
    const float* Wstep = (const float*)d_in[2];
    const float* gK    = (const float*)d_in[3];
    const float* gV    = (const float*)d_in[4];
    const float* lK    = (const float*)d_in[5];
    const float* Wout  = (const float*)d_in[6];
    const unsigned char* mask = (const unsigned char*)d_in[7];
    __hip_bfloat16* out = (__hip_bfloat16*)d_out;

    float* q_ws = (float*)d_ws;   // 512 KB
    query_kernel<<<dim3(NB), dim3(128), 0, stream>>>(ctx, stepc, Wstep, q_ws);
    fused_kernel<<<dim3(NB), dim3(512), 0, stream>>>(q_ws, gK, gV, lK, Wout, mask, out);
}